// Round 1
// baseline (676.210 us; speedup 1.0000x reference)
//
#include <hip/hip_runtime.h>
#include <hip/hip_bf16.h>

// ---------------- types ----------------
typedef __bf16 bf16;
typedef __attribute__((ext_vector_type(8))) __bf16 bf16x8;
typedef __attribute__((ext_vector_type(4))) float f32x4;

#define N_EMB 1024
#define N_HEAD 16
#define HEAD_DIM 64
#define T_SEQ 2048
#define BATCH 2
#define M_TOT (BATCH * T_SEQ)   // 4096
#define N_QKV (3 * N_EMB)       // 3072

// round-to-nearest-even f32 -> bf16 (bit trick; NaN not a concern here)
__device__ inline unsigned short f2bu(float f) {
    unsigned u = __builtin_bit_cast(unsigned, f);
    return (unsigned short)((u + 0x7fffu + ((u >> 16) & 1u)) >> 16);
}
__device__ inline bf16 f2b(float f) {
    unsigned short s = f2bu(f);
    return __builtin_bit_cast(bf16, s);
}

// ---------------- cast x (f32 -> bf16), 4 elems/thread ----------------
__global__ __launch_bounds__(256) void k_cast(const float* __restrict__ x,
                                              bf16* __restrict__ xb, int n4) {
    int i = blockIdx.x * 256 + threadIdx.x;
    if (i < n4) {
        float4 v = reinterpret_cast<const float4*>(x)[i];
        ushort4 u;
        u.x = f2bu(v.x); u.y = f2bu(v.y); u.z = f2bu(v.z); u.w = f2bu(v.w);
        reinterpret_cast<ushort4*>(xb)[i] = u;
    }
}

// ---------------- transpose + cast: W [K][N] f32 -> Wt [N][K] bf16 ----------------
__global__ __launch_bounds__(256) void k_transpose(const float* __restrict__ W,
                                                   bf16* __restrict__ Wt,
                                                   int K, int N) {
    __shared__ float tile[32][33];
    int k0 = blockIdx.x * 32;
    int n0 = blockIdx.y * 32;
    int tx = threadIdx.x & 31;
    int ty = threadIdx.x >> 5;   // 0..7
    for (int j = 0; j < 32; j += 8)
        tile[ty + j][tx] = W[(k0 + ty + j) * N + n0 + tx];
    __syncthreads();
    for (int j = 0; j < 32; j += 8)
        Wt[(n0 + ty + j) * (long)K + k0 + tx] = f2b(tile[tx][ty + j]);
}

// ---------------- QKV GEMM: [4096x1024] @ [1024x3072] + bias -> q/k/v [B,H,T,64] bf16 ----------------
__global__ __launch_bounds__(256) void k_gemm_qkv(const bf16* __restrict__ A,   // [4096][1024]
                                                  const bf16* __restrict__ Bt,  // [3072][1024]
                                                  const float* __restrict__ bias,
                                                  bf16* __restrict__ qb,
                                                  bf16* __restrict__ kb,
                                                  bf16* __restrict__ vb) {
    const int lane = threadIdx.x & 63;
    const int w    = threadIdx.x >> 6;
    const int m0   = blockIdx.x * 16;
    const int n0   = (blockIdx.y * 4 + w) * 16;
    const int r    = lane & 15;
    const int ko   = (lane >> 4) * 8;

    const bf16* ap = A + (m0 + r) * 1024 + ko;
    const bf16* bp = Bt + (n0 + r) * 1024 + ko;
    f32x4 acc = {0.f, 0.f, 0.f, 0.f};
    for (int k = 0; k < 1024; k += 32) {
        bf16x8 a = *reinterpret_cast<const bf16x8*>(ap + k);
        bf16x8 b = *reinterpret_cast<const bf16x8*>(bp + k);
        acc = __builtin_amdgcn_mfma_f32_16x16x32_bf16(a, b, acc, 0, 0, 0);
    }
    // C layout: col = lane&15, row = 4*(lane>>4)+i
    const int col   = lane & 15;
    const int rbase = (lane >> 4) * 4;
    int n = n0 + col;
    float bv = bias[n];
    int which = n >> 10;     // 0:q 1:k 2:v
    int c  = n & 1023;
    int h  = c >> 6;
    int dh = c & 63;
    bf16* dst = (which == 0) ? qb : ((which == 1) ? kb : vb);
    for (int i = 0; i < 4; ++i) {
        int m = m0 + rbase + i;
        int b_ = m >> 11;
        int t  = m & 2047;
        float v = acc[i] + bv;
        dst[(((b_ * N_HEAD + h) * T_SEQ) + t) * HEAD_DIM + dh] = f2b(v);
    }
}

// ---------------- flash attention (causal), one wave = 16 q rows ----------------
__global__ __launch_bounds__(256) void k_attn(const bf16* __restrict__ qb,
                                              const bf16* __restrict__ kb,
                                              const bf16* __restrict__ vb,
                                              bf16* __restrict__ yb) {
    const int lane = threadIdx.x & 63;
    const int w    = threadIdx.x >> 6;
    const int bh   = blockIdx.y;            // 0..31
    const int b    = bh >> 4;
    const int h    = bh & 15;
    const int q0   = blockIdx.x * 64 + w * 16;

    const bf16* Q = qb + (long)bh * T_SEQ * HEAD_DIM;
    const bf16* K = kb + (long)bh * T_SEQ * HEAD_DIM;
    const bf16* V = vb + (long)bh * T_SEQ * HEAD_DIM;

    const int r  = lane & 15;
    const int ko = (lane >> 4) * 8;

    bf16x8 q_lo = *reinterpret_cast<const bf16x8*>(Q + (q0 + r) * HEAD_DIM + ko);
    bf16x8 q_hi = *reinterpret_cast<const bf16x8*>(Q + (q0 + r) * HEAD_DIM + 32 + ko);

    f32x4 zero = {0.f, 0.f, 0.f, 0.f};
    f32x4 o[4] = {zero, zero, zero, zero};
    float m_i[4], l_i[4];
    for (int i = 0; i < 4; ++i) { m_i[i] = -3.0e38f; l_i[i] = 0.f; }

    const int rbase = (lane >> 4) * 4;
    const int col   = lane & 15;

    __shared__ __align__(16) bf16 p_lds[4][16][32];
    bf16 (*pl)[32] = p_lds[w];

    const int nt = (q0 + 15) / 32 + 1;
    const float scale = 0.125f;

    for (int kt = 0; kt < nt; ++kt) {
        const int kbase = kt * 32;
        // ---- S = Q K^T for two 16-col groups ----
        f32x4 s[2];
        for (int g = 0; g < 2; ++g) {
            const bf16* kp = K + (kbase + g * 16 + r) * HEAD_DIM + ko;
            bf16x8 k_lo = *reinterpret_cast<const bf16x8*>(kp);
            bf16x8 k_hi = *reinterpret_cast<const bf16x8*>(kp + 32);
            f32x4 t = zero;
            t = __builtin_amdgcn_mfma_f32_16x16x32_bf16(q_lo, k_lo, t, 0, 0, 0);
            t = __builtin_amdgcn_mfma_f32_16x16x32_bf16(q_hi, k_hi, t, 0, 0, 0);
            s[g] = t;
        }
        // ---- mask + scale, row-max ----
        float mt[4];
        for (int i = 0; i < 4; ++i) {
            int qr = q0 + rbase + i;
            float s0 = s[0][i] * scale;
            float s1 = s[1][i] * scale;
            s0 = (kbase + col)      <= qr ? s0 : -3.0e38f;
            s1 = (kbase + 16 + col) <= qr ? s1 : -3.0e38f;
            s[0][i] = s0; s[1][i] = s1;
            mt[i] = fmaxf(s0, s1);
        }
        for (int msk = 1; msk <= 8; msk <<= 1)
            for (int i = 0; i < 4; ++i)
                mt[i] = fmaxf(mt[i], __shfl_xor(mt[i], msk, 64));
        // ---- online softmax update ----
        float alpha[4], rs[4];
        for (int i = 0; i < 4; ++i) {
            float mn = fmaxf(m_i[i], mt[i]);
            alpha[i] = expf(m_i[i] - mn);
            m_i[i] = mn;
            float p0 = (s[0][i] > -1.0e38f) ? expf(s[0][i] - mn) : 0.f;
            float p1 = (s[1][i] > -1.0e38f) ? expf(s[1][i] - mn) : 0.f;
            s[0][i] = p0; s[1][i] = p1;
            rs[i] = p0 + p1;
        }
        for (int msk = 1; msk <= 8; msk <<= 1)
            for (int i = 0; i < 4; ++i)
                rs[i] += __shfl_xor(rs[i], msk, 64);
        for (int i = 0; i < 4; ++i)
            l_i[i] = l_i[i] * alpha[i] + rs[i];
        for (int dg = 0; dg < 4; ++dg)
            for (int i = 0; i < 4; ++i)
                o[dg][i] *= alpha[i];
        // ---- P: C-layout -> LDS -> A-layout ----
        for (int g = 0; g < 2; ++g)
            for (int i = 0; i < 4; ++i)
                pl[rbase + i][g * 16 + col] = f2b(s[g][i]);
        asm volatile("s_waitcnt lgkmcnt(0)" ::: "memory");
        bf16x8 pa = *reinterpret_cast<const bf16x8*>(&pl[r][ko]);
        // ---- O += P V ----
        for (int dg = 0; dg < 4; ++dg) {
            bf16x8 vf;
            for (int j = 0; j < 8; ++j)
                vf[j] = V[(kbase + ko + j) * HEAD_DIM + dg * 16 + r];
            o[dg] = __builtin_amdgcn_mfma_f32_16x16x32_bf16(pa, vf, o[dg], 0, 0, 0);
        }
    }
    // ---- epilogue: normalize + write y [B,T,C] bf16 ----
    for (int i = 0; i < 4; ++i) {
        int t = q0 + rbase + i;
        float inv = 1.f / l_i[i];
        for (int dg = 0; dg < 4; ++dg) {
            int c = h * HEAD_DIM + dg * 16 + col;
            yb[((long)(b * T_SEQ + t)) * N_EMB + c] = f2b(o[dg][i] * inv);
        }
    }
}

// ---------------- proj GEMM: y[4096x1024] @ Wp[1024x1024] + bias -> out f32 ----------------
__global__ __launch_bounds__(256) void k_gemm_proj(const bf16* __restrict__ A,   // [4096][1024]
                                                   const bf16* __restrict__ Bt,  // [1024][1024]
                                                   const float* __restrict__ bias,
                                                   float* __restrict__ out) {
    const int lane = threadIdx.x & 63;
    const int w    = threadIdx.x >> 6;
    const int m0   = blockIdx.x * 16;
    const int n0   = (blockIdx.y * 4 + w) * 16;
    const int r    = lane & 15;
    const int ko   = (lane >> 4) * 8;

    const bf16* ap = A + (m0 + r) * 1024 + ko;
    const bf16* bp = Bt + (n0 + r) * 1024 + ko;
    f32x4 acc = {0.f, 0.f, 0.f, 0.f};
    for (int k = 0; k < 1024; k += 32) {
        bf16x8 a = *reinterpret_cast<const bf16x8*>(ap + k);
        bf16x8 b = *reinterpret_cast<const bf16x8*>(bp + k);
        acc = __builtin_amdgcn_mfma_f32_16x16x32_bf16(a, b, acc, 0, 0, 0);
    }
    const int col   = lane & 15;
    const int rbase = (lane >> 4) * 4;
    int n = n0 + col;
    float bv = bias[n];
    for (int i = 0; i < 4; ++i) {
        int m = m0 + rbase + i;
        out[(long)m * N_EMB + n] = acc[i] + bv;
    }
}

extern "C" void kernel_launch(void* const* d_in, const int* in_sizes, int n_in,
                              void* d_out, int out_size, void* d_ws, size_t ws_size,
                              hipStream_t stream) {
    const float* x      = (const float*)d_in[0];
    const float* W_attn = (const float*)d_in[1];
    const float* b_attn = (const float*)d_in[2];
    const float* W_proj = (const float*)d_in[3];
    const float* b_proj = (const float*)d_in[4];
    float* out = (float*)d_out;

    // workspace layout (bf16 elements)
    const size_t sz_x   = (size_t)M_TOT * N_EMB;        // 4096*1024
    const size_t sz_wat = (size_t)N_QKV * N_EMB;        // 3072*1024
    const size_t sz_wpt = (size_t)N_EMB * N_EMB;        // 1024*1024
    const size_t sz_hd  = (size_t)BATCH * N_HEAD * T_SEQ * HEAD_DIM; // 4096*1024
    const size_t need = (sz_x + sz_wat + sz_wpt + 3 * sz_hd + sz_x) * sizeof(bf16);
    if (ws_size < need) return; // fail loudly via wrong output rather than corrupt

    bf16* xb  = (bf16*)d_ws;
    bf16* wat = xb + sz_x;
    bf16* wpt = wat + sz_wat;
    bf16* qb  = wpt + sz_wpt;
    bf16* kbf = qb + sz_hd;
    bf16* vbf = kbf + sz_hd;
    bf16* yb  = vbf + sz_hd;

    k_cast<<<dim3((sz_x / 4 + 255) / 256), 256, 0, stream>>>(x, xb, (int)(sz_x / 4));
    k_transpose<<<dim3(N_EMB / 32, N_QKV / 32), 256, 0, stream>>>(W_attn, wat, N_EMB, N_QKV);
    k_transpose<<<dim3(N_EMB / 32, N_EMB / 32), 256, 0, stream>>>(W_proj, wpt, N_EMB, N_EMB);
    k_gemm_qkv<<<dim3(M_TOT / 16, N_QKV / 64), 256, 0, stream>>>(xb, wat, b_attn, qb, kbf, vbf);
    k_attn<<<dim3(T_SEQ / 64, BATCH * N_HEAD), 256, 0, stream>>>(qb, kbf, vbf, yb);
    k_gemm_proj<<<dim3(M_TOT / 16, N_EMB / 64), 256, 0, stream>>>(yb, wpt, b_proj, out);
}

// Round 2
// 280.228 us; speedup vs baseline: 2.4131x; 2.4131x over previous
//
#include <hip/hip_runtime.h>
#include <hip/hip_bf16.h>

// ---------------- types ----------------
typedef __bf16 bf16;
typedef __attribute__((ext_vector_type(8))) __bf16 bf16x8;
typedef __attribute__((ext_vector_type(4))) float f32x4;
typedef unsigned int u32;
typedef const __attribute__((address_space(1))) u32* gptr_t;
typedef __attribute__((address_space(3))) u32* lptr_t;

#define N_EMB 1024
#define N_HEAD 16
#define HEAD_DIM 64
#define T_SEQ 2048
#define BATCH 2
#define M_TOT (BATCH * T_SEQ)   // 4096
#define N_QKV (3 * N_EMB)       // 3072
#define KDIM 1024

// round-to-nearest-even f32 -> bf16
__device__ inline unsigned short f2bu(float f) {
    unsigned u = __builtin_bit_cast(unsigned, f);
    return (unsigned short)((u + 0x7fffu + ((u >> 16) & 1u)) >> 16);
}
__device__ inline bf16 f2b(float f) {
    unsigned short s = f2bu(f);
    return __builtin_bit_cast(bf16, s);
}

// ---------------- cast x (f32 -> bf16), 4 elems/thread ----------------
__global__ __launch_bounds__(256) void k_cast(const float* __restrict__ x,
                                              bf16* __restrict__ xb, int n4) {
    int i = blockIdx.x * 256 + threadIdx.x;
    if (i < n4) {
        float4 v = reinterpret_cast<const float4*>(x)[i];
        ushort4 u;
        u.x = f2bu(v.x); u.y = f2bu(v.y); u.z = f2bu(v.z); u.w = f2bu(v.w);
        reinterpret_cast<ushort4*>(xb)[i] = u;
    }
}

// ---------------- transpose + cast: W [K][N] f32 -> Wt [N][K] bf16 ----------------
__global__ __launch_bounds__(256) void k_transpose(const float* __restrict__ W,
                                                   bf16* __restrict__ Wt,
                                                   int K, int N) {
    __shared__ float tile[32][33];
    int k0 = blockIdx.x * 32;
    int n0 = blockIdx.y * 32;
    int tx = threadIdx.x & 31;
    int ty = threadIdx.x >> 5;   // 0..7
    for (int j = 0; j < 32; j += 8)
        tile[ty + j][tx] = W[(k0 + ty + j) * N + n0 + tx];
    __syncthreads();
    for (int j = 0; j < 32; j += 8)
        Wt[(n0 + ty + j) * (long)K + k0 + tx] = f2b(tile[tx][ty + j]);
}

// =====================================================================
// m97-structure GEMM main loop: 128x128 tile, 4 waves, BK=32,
// global_load_lds width-16 staging, 2 barriers/K-step, acc[4][4].
// A [M][1024] bf16 row-major, Bt [N][1024] bf16 row-major (B transposed).
// Wave w owns the 64x64 sub-tile at (wr*64, wc*64), wr=w>>1, wc=w&1.
// =====================================================================
#define GEMM_MAINLOOP(A_, Bt_, m0_, n0_)                                          \
    __shared__ __align__(16) bf16 As[128 * 32];                                   \
    __shared__ __align__(16) bf16 Bs[128 * 32];                                   \
    const int lane = threadIdx.x & 63;                                            \
    const int w    = threadIdx.x >> 6;                                            \
    const int wr   = w >> 1;                                                      \
    const int wc   = w & 1;                                                       \
    const int r    = lane & 15;                                                   \
    const int ko   = (lane >> 4) * 8;                                             \
    /* staging: wave w handles chunks w*2, w*2+1 (16 rows x 32k each) */          \
    const int srow = w * 32 + (lane >> 2);                                        \
    const int sk   = (lane & 3) * 8;                                              \
    const bf16* a_g0 = A_ + (size_t)(m0_ + srow) * KDIM + sk;                     \
    const bf16* a_g1 = a_g0 + 16 * KDIM;                                          \
    const bf16* b_g0 = Bt_ + (size_t)(n0_ + srow) * KDIM + sk;                    \
    const bf16* b_g1 = b_g0 + 16 * KDIM;                                          \
    bf16* a_l0 = As + (w * 2) * 512;                                              \
    bf16* a_l1 = As + (w * 2 + 1) * 512;                                          \
    bf16* b_l0 = Bs + (w * 2) * 512;                                              \
    bf16* b_l1 = Bs + (w * 2 + 1) * 512;                                          \
    f32x4 acc[4][4];                                                              \
    for (int i = 0; i < 4; ++i)                                                   \
        for (int j = 0; j < 4; ++j) acc[i][j] = (f32x4){0.f, 0.f, 0.f, 0.f};      \
    for (int k0 = 0; k0 < KDIM; k0 += 32) {                                       \
        __builtin_amdgcn_global_load_lds((gptr_t)(const void*)(a_g0 + k0),        \
                                         (lptr_t)(void*)a_l0, 16, 0, 0);          \
        __builtin_amdgcn_global_load_lds((gptr_t)(const void*)(a_g1 + k0),        \
                                         (lptr_t)(void*)a_l1, 16, 0, 0);          \
        __builtin_amdgcn_global_load_lds((gptr_t)(const void*)(b_g0 + k0),        \
                                         (lptr_t)(void*)b_l0, 16, 0, 0);          \
        __builtin_amdgcn_global_load_lds((gptr_t)(const void*)(b_g1 + k0),        \
                                         (lptr_t)(void*)b_l1, 16, 0, 0);          \
        __syncthreads();                                                          \
        bf16x8 af[4], bfr[4];                                                     \
        for (int m = 0; m < 4; ++m)                                               \
            af[m] = *reinterpret_cast<const bf16x8*>(As + (wr * 64 + m * 16 + r) * 32 + ko); \
        for (int n = 0; n < 4; ++n)                                               \
            bfr[n] = *reinterpret_cast<const bf16x8*>(Bs + (wc * 64 + n * 16 + r) * 32 + ko); \
        for (int m = 0; m < 4; ++m)                                               \
            for (int n = 0; n < 4; ++n)                                           \
                acc[m][n] = __builtin_amdgcn_mfma_f32_16x16x32_bf16(af[m], bfr[n], acc[m][n], 0, 0, 0); \
        __syncthreads();                                                          \
    }

// ---------------- QKV GEMM: x[4096x1024] @ W[1024x3072] + bias -> q/k/v [B,H,T,64] bf16
__global__ __launch_bounds__(256) void k_gemm_qkv(const bf16* __restrict__ A,
                                                  const bf16* __restrict__ Bt,
                                                  const float* __restrict__ bias,
                                                  bf16* __restrict__ qb,
                                                  bf16* __restrict__ kb,
                                                  bf16* __restrict__ vb) {
    const int m0 = blockIdx.x * 128;
    const int n0 = blockIdx.y * 128;
    GEMM_MAINLOOP(A, Bt, m0, n0)
    // epilogue: C layout col=lane&15, row=4*(lane>>4)+i
    const int col   = lane & 15;
    const int rbase = (lane >> 4) * 4;
    for (int nn = 0; nn < 4; ++nn) {
        int n = n0 + wc * 64 + nn * 16 + col;
        float bv = bias[n];
        int which = n >> 10;     // 0:q 1:k 2:v
        int c  = n & 1023;
        int h  = c >> 6;
        int dh = c & 63;
        bf16* dst = (which == 0) ? qb : ((which == 1) ? kb : vb);
        for (int mm = 0; mm < 4; ++mm) {
            for (int i = 0; i < 4; ++i) {
                int m = m0 + wr * 64 + mm * 16 + rbase + i;
                int b_ = m >> 11;
                int t  = m & 2047;
                dst[(((b_ * N_HEAD + h) * T_SEQ) + t) * HEAD_DIM + dh] =
                    f2b(acc[mm][nn][i] + bv);
            }
        }
    }
}

// ---------------- proj GEMM: y[4096x1024] @ Wp[1024x1024] + bias -> out f32
__global__ __launch_bounds__(256) void k_gemm_proj(const bf16* __restrict__ A,
                                                   const bf16* __restrict__ Bt,
                                                   const float* __restrict__ bias,
                                                   float* __restrict__ out) {
    const int m0 = blockIdx.x * 128;
    const int n0 = blockIdx.y * 128;
    GEMM_MAINLOOP(A, Bt, m0, n0)
    const int col   = lane & 15;
    const int rbase = (lane >> 4) * 4;
    for (int nn = 0; nn < 4; ++nn) {
        int n = n0 + wc * 64 + nn * 16 + col;
        float bv = bias[n];
        for (int mm = 0; mm < 4; ++mm) {
            for (int i = 0; i < 4; ++i) {
                int m = m0 + wr * 64 + mm * 16 + rbase + i;
                out[(size_t)m * N_EMB + n] = acc[mm][nn][i] + bv;
            }
        }
    }
}

// ---------------- flash attention (causal), one wave = 16 q rows ----------------
__global__ __launch_bounds__(256) void k_attn(const bf16* __restrict__ qb,
                                              const bf16* __restrict__ kb,
                                              const bf16* __restrict__ vb,
                                              bf16* __restrict__ yb) {
    const int lane = threadIdx.x & 63;
    const int w    = threadIdx.x >> 6;
    const int bh   = blockIdx.y;            // 0..31
    const int b    = bh >> 4;
    const int h    = bh & 15;
    const int q0   = blockIdx.x * 64 + w * 16;

    const bf16* Q = qb + (long)bh * T_SEQ * HEAD_DIM;
    const bf16* K = kb + (long)bh * T_SEQ * HEAD_DIM;
    const bf16* V = vb + (long)bh * T_SEQ * HEAD_DIM;

    const int r  = lane & 15;
    const int ko = (lane >> 4) * 8;

    bf16x8 q_lo = *reinterpret_cast<const bf16x8*>(Q + (q0 + r) * HEAD_DIM + ko);
    bf16x8 q_hi = *reinterpret_cast<const bf16x8*>(Q + (q0 + r) * HEAD_DIM + 32 + ko);

    f32x4 zero = {0.f, 0.f, 0.f, 0.f};
    f32x4 o[4] = {zero, zero, zero, zero};
    float m_i[4], l_i[4];
    for (int i = 0; i < 4; ++i) { m_i[i] = -3.0e38f; l_i[i] = 0.f; }

    const int rbase = (lane >> 4) * 4;
    const int col   = lane & 15;

    __shared__ __align__(16) bf16 p_lds[4][16][32];
    bf16 (*pl)[32] = p_lds[w];

    const int nt = (q0 + 15) / 32 + 1;
    const float scale = 0.125f;

    for (int kt = 0; kt < nt; ++kt) {
        const int kbase = kt * 32;
        f32x4 s[2];
        for (int g = 0; g < 2; ++g) {
            const bf16* kp = K + (kbase + g * 16 + r) * HEAD_DIM + ko;
            bf16x8 k_lo = *reinterpret_cast<const bf16x8*>(kp);
            bf16x8 k_hi = *reinterpret_cast<const bf16x8*>(kp + 32);
            f32x4 t = zero;
            t = __builtin_amdgcn_mfma_f32_16x16x32_bf16(q_lo, k_lo, t, 0, 0, 0);
            t = __builtin_amdgcn_mfma_f32_16x16x32_bf16(q_hi, k_hi, t, 0, 0, 0);
            s[g] = t;
        }
        float mt[4];
        for (int i = 0; i < 4; ++i) {
            int qr = q0 + rbase + i;
            float s0 = s[0][i] * scale;
            float s1 = s[1][i] * scale;
            s0 = (kbase + col)      <= qr ? s0 : -3.0e38f;
            s1 = (kbase + 16 + col) <= qr ? s1 : -3.0e38f;
            s[0][i] = s0; s[1][i] = s1;
            mt[i] = fmaxf(s0, s1);
        }
        for (int msk = 1; msk <= 8; msk <<= 1)
            for (int i = 0; i < 4; ++i)
                mt[i] = fmaxf(mt[i], __shfl_xor(mt[i], msk, 64));
        float alpha[4], rs[4];
        for (int i = 0; i < 4; ++i) {
            float mn = fmaxf(m_i[i], mt[i]);
            alpha[i] = expf(m_i[i] - mn);
            m_i[i] = mn;
            float p0 = (s[0][i] > -1.0e38f) ? expf(s[0][i] - mn) : 0.f;
            float p1 = (s[1][i] > -1.0e38f) ? expf(s[1][i] - mn) : 0.f;
            s[0][i] = p0; s[1][i] = p1;
            rs[i] = p0 + p1;
        }
        for (int msk = 1; msk <= 8; msk <<= 1)
            for (int i = 0; i < 4; ++i)
                rs[i] += __shfl_xor(rs[i], msk, 64);
        for (int i = 0; i < 4; ++i)
            l_i[i] = l_i[i] * alpha[i] + rs[i];
        for (int dg = 0; dg < 4; ++dg)
            for (int i = 0; i < 4; ++i)
                o[dg][i] *= alpha[i];
        for (int g = 0; g < 2; ++g)
            for (int i = 0; i < 4; ++i)
                pl[rbase + i][g * 16 + col] = f2b(s[g][i]);
        asm volatile("s_waitcnt lgkmcnt(0)" ::: "memory");
        bf16x8 pa = *reinterpret_cast<const bf16x8*>(&pl[r][ko]);
        for (int dg = 0; dg < 4; ++dg) {
            bf16x8 vf;
            for (int j = 0; j < 8; ++j)
                vf[j] = V[(kbase + ko + j) * HEAD_DIM + dg * 16 + r];
            o[dg] = __builtin_amdgcn_mfma_f32_16x16x32_bf16(pa, vf, o[dg], 0, 0, 0);
        }
    }
    for (int i = 0; i < 4; ++i) {
        int t = q0 + rbase + i;
        float inv = 1.f / l_i[i];
        for (int dg = 0; dg < 4; ++dg) {
            int c = h * HEAD_DIM + dg * 16 + col;
            yb[((long)(b * T_SEQ + t)) * N_EMB + c] = f2b(o[dg][i] * inv);
        }
    }
}

extern "C" void kernel_launch(void* const* d_in, const int* in_sizes, int n_in,
                              void* d_out, int out_size, void* d_ws, size_t ws_size,
                              hipStream_t stream) {
    const float* x      = (const float*)d_in[0];
    const float* W_attn = (const float*)d_in[1];
    const float* b_attn = (const float*)d_in[2];
    const float* W_proj = (const float*)d_in[3];
    const float* b_proj = (const float*)d_in[4];
    float* out = (float*)d_out;

    const size_t sz_x   = (size_t)M_TOT * N_EMB;
    const size_t sz_wat = (size_t)N_QKV * N_EMB;
    const size_t sz_wpt = (size_t)N_EMB * N_EMB;
    const size_t sz_hd  = (size_t)BATCH * N_HEAD * T_SEQ * HEAD_DIM;
    const size_t need = (sz_x + sz_wat + sz_wpt + 3 * sz_hd + sz_x) * sizeof(bf16);
    if (ws_size < need) return;

    bf16* xb  = (bf16*)d_ws;
    bf16* wat = xb + sz_x;
    bf16* wpt = wat + sz_wat;
    bf16* qb  = wpt + sz_wpt;
    bf16* kbf = qb + sz_hd;
    bf16* vbf = kbf + sz_hd;
    bf16* yb  = vbf + sz_hd;

    k_cast<<<dim3((sz_x / 4 + 255) / 256), 256, 0, stream>>>(x, xb, (int)(sz_x / 4));
    k_transpose<<<dim3(N_EMB / 32, N_QKV / 32), 256, 0, stream>>>(W_attn, wat, N_EMB, N_QKV);
    k_transpose<<<dim3(N_EMB / 32, N_EMB / 32), 256, 0, stream>>>(W_proj, wpt, N_EMB, N_EMB);
    k_gemm_qkv<<<dim3(M_TOT / 128, N_QKV / 128), 256, 0, stream>>>(xb, wat, b_attn, qb, kbf, vbf);
    k_attn<<<dim3(T_SEQ / 64, BATCH * N_HEAD), 256, 0, stream>>>(qb, kbf, vbf, yb);
    k_gemm_proj<<<dim3(M_TOT / 128, N_EMB / 128), 256, 0, stream>>>(yb, wpt, b_proj, out);
}